// Round 8
// baseline (99.812 us; speedup 1.0000x reference)
//
#include <hip/hip_runtime.h>

// SoftMinLayer via MFMA — R8: R7 + j-halved waves (896 thr) for 2x residency.
// Numerics R5/R7-VERBATIM (HW-proven):
//   pass 1: hi*hi MFMA -> approximate per-k min reference mq (no exps)
//   pass 2: full 3-term bf16 hi/lo MFMA; w = exp2f(t*CQ), t = q - mq;
//           track exact tmin; out = (T/S - tmin)/L  (shift-exact).
// Decomposition: 14 waves; wave w owns k-tile nt=w%7 and j-half jh=w/7
// (mt = jh, jh+2, ...). Pass-1 mins merged across halves via LDS so both
// halves share ONE reference mq (plain-sum merge stays exact). Grid was the
// binding limit in R7 (14 waves/CU); now 28/CU. Per-CU LDS/MFMA/VALU totals
// unchanged. Reg budget: need <=64 total/wave for 28 waves/CU (m69 halving
// points); R7 measured 40 with identical per-wave state.

#define N_SEQ   512
#define Q_LEN   1024
#define K_SH    100
#define L_SH    50
#define J_WIN   974              // Q - L
#define NTILE   7                // k-tiles
#define MTILES  61               // j-tiles (976 rows incl 2 pad)
#define RINV_L  0.02f            // 1/50
#define PAD_SQ  4e31f            // sq_win pad -> w = exp2f(-1.15e32) = 0 exactly
#define CQ      (-2.8853900817779268f)   // ALPHA * log2(e) / L = -2*log2(e)

#define CPR     1064             // region stride (elems) for shifted copies

typedef short  short8 __attribute__((ext_vector_type(8)));
typedef float  f32x4  __attribute__((ext_vector_type(4)));
typedef unsigned int uintx4 __attribute__((ext_vector_type(4)));

union V8 { short8 s; uintx4 u; };

__device__ __forceinline__ unsigned int bf16h(float f) {
    unsigned int b = __float_as_uint(f);
    return (b + 0x7FFFu + ((b >> 16) & 1u)) >> 16;   // RNE to bf16 (finite inputs)
}
__device__ __forceinline__ float bf16back(unsigned int h) {
    return __uint_as_float(h << 16);
}

__global__ __launch_bounds__(896, 2)
void softmin_mfma_kernel(const float* __restrict__ x,
                         const float* __restrict__ sh,
                         float* __restrict__ out) {
    // 16 regions (r=0..7 x half=hi/lo) of CPR shorts: cp[(2r+half)*CPR + e] = x_half[e + r]
    __shared__ __align__(16) short cp[16 * CPR];          // 34,048 B
    __shared__ __align__(16) float lds_xf[1056];          //  4,224 B
    __shared__ __align__(16) float lds_sqw[984];          //  3,936 B (974.. = PAD_SQ)
    __shared__ __align__(16) float gmT[2 * NTILE * 16];   //    896 B  pass-1 mins per half
    __shared__ __align__(16) float redM[2 * NTILE * 16];  //    896 B  pass-2 tmin per half
    __shared__ __align__(16) float redS[2 * NTILE * 16];  //    896 B
    __shared__ __align__(16) float redT[2 * NTILE * 16];  //    896 B
    // total 45,792 B -> 2 blocks/CU (91.6 KB), 28 waves/CU if regs <= 64

    const int i    = blockIdx.x;
    const int tid  = threadIdx.x;
    const int lane = tid & 63;
    const int w    = tid >> 6;     // wave 0..13
    const int jh   = (w >= NTILE) ? 1 : 0;
    const int nt   = w - NTILE * jh;   // k-tile 0..6
    const int g    = lane >> 4;    // 0..3
    const int bcol = lane & 15;

    // ---- B fragments for THIS wave's k-tile (nt), R5-verbatim values ----
    // B[kappa][n]: lane holds kappa = l0 + 8g + i (i=0..7), n = nt*16 + bcol.
    short8 bh0, bh1, blo0, blo1;
    {
        const int n = nt * 16 + bcol;
        float sv[16];
        #pragma unroll
        for (int e = 0; e < 16; ++e) sv[e] = 0.f;
        if (n < K_SH) {
            const float* srow = sh + n * L_SH;
            const float2* p0 = (const float2*)(srow + 8 * g);        // kappa 8g..8g+7 (<32)
            #pragma unroll
            for (int q = 0; q < 4; ++q) { float2 v = p0[q]; sv[2*q] = v.x; sv[2*q+1] = v.y; }
            if (g < 2) {                                             // kappa 32+8g..+7 (<48)
                const float2* p1 = (const float2*)(srow + 32 + 8 * g);
                #pragma unroll
                for (int q = 0; q < 4; ++q) { float2 v = p1[q]; sv[8+2*q] = v.x; sv[9+2*q] = v.y; }
            } else if (g == 2) {                                     // kappa 48,49 real
                float2 v = *(const float2*)(srow + 48);
                sv[8] = v.x; sv[9] = v.y;
            }                                                        // g==3 hi-half: all >=50 -> 0
        }
        unsigned int hb[16], lb[16];
        #pragma unroll
        for (int e = 0; e < 16; ++e) {
            hb[e] = bf16h(sv[e]);
            lb[e] = bf16h(sv[e] - bf16back(hb[e]));
        }
        V8 a, b, c, d;
        a.u = uintx4{hb[0]|(hb[1]<<16),  hb[2]|(hb[3]<<16),  hb[4]|(hb[5]<<16),  hb[6]|(hb[7]<<16)};
        b.u = uintx4{hb[8]|(hb[9]<<16),  hb[10]|(hb[11]<<16),hb[12]|(hb[13]<<16),hb[14]|(hb[15]<<16)};
        c.u = uintx4{lb[0]|(lb[1]<<16),  lb[2]|(lb[3]<<16),  lb[4]|(lb[5]<<16),  lb[6]|(lb[7]<<16)};
        d.u = uintx4{lb[8]|(lb[9]<<16),  lb[10]|(lb[11]<<16),lb[12]|(lb[13]<<16),lb[14]|(lb[15]<<16)};
        bh0 = a.s; bh1 = b.s; blo0 = c.s; blo1 = d.s;
    }

    // ---- stage x row (f32) into LDS, zero-pad to 1056 ----
    {
        const float4* gx = (const float4*)(x + (size_t)i * Q_LEN);
        float4* lx = (float4*)lds_xf;
        if (tid < 256) lx[tid] = gx[tid];
        if (tid < 8)   lx[256 + tid] = make_float4(0.f, 0.f, 0.f, 0.f);
    }
    __syncthreads();

    // ---- sq_win (exact fp32, sliding within groups of 4) ----
    if (tid < 246) {
        const float4* xf4 = (const float4*)lds_xf;
        float r0, r1, r2, r3;
        if (tid < 244) {
            float v[56];
            #pragma unroll
            for (int q = 0; q < 14; ++q) {
                float4 a = xf4[tid + q];
                v[4*q] = a.x; v[4*q+1] = a.y; v[4*q+2] = a.z; v[4*q+3] = a.w;
            }
            float s0 = 0.f;
            #pragma unroll
            for (int l = 0; l < L_SH; ++l) s0 = fmaf(v[l], v[l], s0);
            float s1 = fmaf(v[50], v[50], s0 - v[0]*v[0]);
            float s2 = fmaf(v[51], v[51], s1 - v[1]*v[1]);
            float s3 = fmaf(v[52], v[52], s2 - v[2]*v[2]);
            r0 = s0; r1 = s1; r2 = s2; r3 = s3;
            if (4*tid + 2 >= J_WIN) r2 = PAD_SQ;            // j = 974
            if (4*tid + 3 >= J_WIN) r3 = PAD_SQ;            // j = 975
        } else {
            r0 = r1 = r2 = r3 = PAD_SQ;                     // j 976..983
        }
        *(float4*)&lds_sqw[4*tid] = make_float4(r0, r1, r2, r3);
    }

    // ---- base bf16 hi/lo arrays (copy r=0) ----
    if (tid < 132) {
        const float4* xf4 = (const float4*)lds_xf;
        float4 a = xf4[2*tid], b = xf4[2*tid + 1];
        float xv[8] = {a.x, a.y, a.z, a.w, b.x, b.y, b.z, b.w};
        unsigned int hh[8], rr[8];
        #pragma unroll
        for (int e = 0; e < 8; ++e) {
            hh[e] = bf16h(xv[e]);
            rr[e] = bf16h(xv[e] - bf16back(hh[e]));
        }
        *(uintx4*)&cp[8*tid] =
            uintx4{hh[0]|(hh[1]<<16), hh[2]|(hh[3]<<16), hh[4]|(hh[5]<<16), hh[6]|(hh[7]<<16)};
        *(uintx4*)&cp[CPR + 8*tid] =
            uintx4{rr[0]|(rr[1]<<16), rr[2]|(rr[3]<<16), rr[4]|(rr[5]<<16), rr[6]|(rr[7]<<16)};
    }
    __syncthreads();

    // ---- shifted copies r=1..7 via aligned reads + 16-bit funnel shifts ----
    if (tid < 262) {                                         // 131 blocks x 2 halves
        const int half = tid & 1, blk = tid >> 1;
        const uintx4 A  = *(const uintx4*)&cp[half*CPR + 8*blk];
        const uintx4 B4 = *(const uintx4*)&cp[half*CPR + 8*blk + 8];
        unsigned int s[8] = {A[0], A[1], A[2], A[3], B4[0], B4[1], B4[2], B4[3]};
        #pragma unroll
        for (int r = 1; r < 8; ++r) {
            const int p = r >> 1;
            unsigned int o[4];
            if ((r & 1) == 0) {
                #pragma unroll
                for (int e = 0; e < 4; ++e) o[e] = s[p + e];
            } else {
                #pragma unroll
                for (int e = 0; e < 4; ++e) o[e] = (s[p + e] >> 16) | (s[p + e + 1] << 16);
            }
            *(uintx4*)&cp[(2*r + half)*CPR + 8*blk] = uintx4{o[0], o[1], o[2], o[3]};
        }
    }
    __syncthreads();

    // A frag elem i <-> x[j0 + (lane&15) + l0 + 8g + i]; start == lane (mod 8)
    // -> copy r = lane&7 at 8-aligned elem (j0 + l0 + 8*((lane>>3)&1) + 8g).
    const int r7       = lane & 7;
    const int lane_off = 8 * ((lane >> 3) & 1) + 8 * g;
    const int abase0   = (2 * r7) * CPR + lane_off;

    // ======== PASS 1: hi*hi approximate min over THIS HALF's j-tiles ========
    float mreg = 1e30f;
    for (int mt = jh; mt < MTILES; mt += 2) {
        const int j0 = mt << 4;
        const int ae = abase0 + j0;
        const short8 ah0 = *(const short8*)&cp[ae];
        const short8 ah1 = *(const short8*)&cp[ae + 32];
        const float4 sqv = *(const float4*)&lds_sqw[j0 + 4 * g];

        f32x4 a0 = {0.f, 0.f, 0.f, 0.f}, a1 = {0.f, 0.f, 0.f, 0.f};
        a0 = __builtin_amdgcn_mfma_f32_16x16x32_bf16(ah0, bh0, a0, 0, 0, 0);
        a1 = __builtin_amdgcn_mfma_f32_16x16x32_bf16(ah1, bh1, a1, 0, 0, 0);
        const float q0 = fmaf(a0[0], -2.f, fmaf(a1[0], -2.f, sqv.x));
        const float q1 = fmaf(a0[1], -2.f, fmaf(a1[1], -2.f, sqv.y));
        const float q2 = fmaf(a0[2], -2.f, fmaf(a1[2], -2.f, sqv.z));
        const float q3 = fmaf(a0[3], -2.f, fmaf(a1[3], -2.f, sqv.w));
        mreg = fminf(mreg, fminf(fminf(q0, q1), fminf(q2, q3)));
    }
    mreg = fminf(mreg, __shfl_xor(mreg, 16));
    mreg = fminf(mreg, __shfl_xor(mreg, 32));
    if (lane < 16) gmT[(jh * NTILE + nt) * 16 + lane] = mreg;
    __syncthreads();
    // global (both halves) reference min for this k-column
    const float mq = fminf(gmT[nt * 16 + bcol], gmT[(NTILE + nt) * 16 + bcol]);

    // ======== PASS 2: full 6-MFMA GEMM + branchless weights (R5 math) ========
    float S = 0.f, T = 0.f, tmin = 1e30f;
    for (int mt = jh; mt < MTILES; mt += 2) {
        const int j0 = mt << 4;
        const int ae = abase0 + j0;
        const short8 ah0 = *(const short8*)&cp[ae];
        const short8 ah1 = *(const short8*)&cp[ae + 32];
        const short8 al0 = *(const short8*)&cp[ae + CPR];
        const short8 al1 = *(const short8*)&cp[ae + CPR + 32];
        const float4 sqv = *(const float4*)&lds_sqw[j0 + 4 * g];

        f32x4 a0 = {0.f, 0.f, 0.f, 0.f}, a1 = {0.f, 0.f, 0.f, 0.f};
        a0 = __builtin_amdgcn_mfma_f32_16x16x32_bf16(ah0, bh0,  a0, 0, 0, 0);
        a1 = __builtin_amdgcn_mfma_f32_16x16x32_bf16(ah1, bh1,  a1, 0, 0, 0);
        a0 = __builtin_amdgcn_mfma_f32_16x16x32_bf16(al0, bh0,  a0, 0, 0, 0);
        a1 = __builtin_amdgcn_mfma_f32_16x16x32_bf16(al1, bh1,  a1, 0, 0, 0);
        a0 = __builtin_amdgcn_mfma_f32_16x16x32_bf16(ah0, blo0, a0, 0, 0, 0);
        a1 = __builtin_amdgcn_mfma_f32_16x16x32_bf16(ah1, blo1, a1, 0, 0, 0);

        const float t0 = fmaf(a0[0], -2.f, fmaf(a1[0], -2.f, sqv.x - mq));
        const float t1 = fmaf(a0[1], -2.f, fmaf(a1[1], -2.f, sqv.y - mq));
        const float t2 = fmaf(a0[2], -2.f, fmaf(a1[2], -2.f, sqv.z - mq));
        const float t3 = fmaf(a0[3], -2.f, fmaf(a1[3], -2.f, sqv.w - mq));
        tmin = fminf(tmin, fminf(fminf(t0, t1), fminf(t2, t3)));

        const float w0 = exp2f(t0 * CQ);
        const float w1 = exp2f(t1 * CQ);
        const float w2 = exp2f(t2 * CQ);
        const float w3 = exp2f(t3 * CQ);
        S += (w0 + w1) + (w2 + w3);
        float tv = T;
        tv = fmaf(t0, w0, tv);
        tv = fmaf(t1, w1, tv);
        tv = fmaf(t2, w2, tv);
        tv = fmaf(t3, w3, tv);
        T = tv;
    }

    // ---- wave-local reduce (all lanes share mq -> plain sums) ----
    tmin = fminf(tmin, __shfl_xor(tmin, 16));
    tmin = fminf(tmin, __shfl_xor(tmin, 32));
    S += __shfl_xor(S, 16);  S += __shfl_xor(S, 32);
    T += __shfl_xor(T, 16);  T += __shfl_xor(T, 32);
    if (lane < 16) {
        const int idx = (jh * NTILE + nt) * 16 + lane;
        redM[idx] = tmin; redS[idx] = S; redT[idx] = T;
    }
    __syncthreads();

    // ---- merge the two j-halves + write:  M = (T/S - tmin) / L ----
    if (tid < NTILE * 16) {
        const int hi2 = (NTILE * 16) + tid;
        const float tm = fminf(redM[tid], redM[hi2]);
        const float Sf = redS[tid] + redS[hi2];
        const float Tf = redT[tid] + redT[hi2];
        // k = (tid>>4)*16 + (tid&15) == tid
        if (tid < K_SH) out[(size_t)i * K_SH + tid] = (Tf / Sf - tm) * RINV_L;
    }
}

extern "C" void kernel_launch(void* const* d_in, const int* in_sizes, int n_in,
                              void* d_out, int out_size, void* d_ws, size_t ws_size,
                              hipStream_t stream) {
    const float* x  = (const float*)d_in[0];   // (512, 1024) f32
    const float* sh = (const float*)d_in[1];   // (100, 50)  f32
    float* out = (float*)d_out;                // (512, 100) f32

    softmin_mfma_kernel<<<N_SEQ, 896, 0, stream>>>(x, sh, out);
}

// Round 9
// 91.145 us; speedup vs baseline: 1.0951x; 1.0951x over previous
//
#include <hip/hip_runtime.h>

// SoftMinLayer via MFMA — R9: 32x32x16 MFMA to cut LDS traffic 2.3x.
// R8 showed the kernel is LDS-throughput-bound (7 k-waves re-read all A-frags:
// ~34 us/CU of ds_read_b128; occupancy increase regressed). 32-wide k-tiles
// need only 4 waves -> A redundancy 7->4 and same per-row rate.
// Numerics R5/R7-VERBATIM: pass1 hi*hi -> approx min ref mq; pass2 3-term
// hi/lo, w = exp2f(t*CQ), t = q - mq, exact tmin; out = (T/S - tmin)/L.
// Layouts: C/D 32x32 verified (col=lane&31, row=(reg&3)+8(reg>>2)+4(lane>>5));
// A/B mirror our verified 16x16x32 pattern (row/col = lane mod M, k-block =
// lane div M). 512 thr = 8 waves = 4 k-tiles x 2 j-halves.

#define N_SEQ   512
#define Q_LEN   1024
#define K_SH    100
#define L_SH    50
#define J_WIN   974              // Q - L
#define MT32    31               // j-tiles of 32 rows (992 incl 18 pad)
#define RINV_L  0.02f            // 1/50
#define PAD_SQ  4e31f            // sq_win pad -> w = exp2f(-1.15e32) = 0 exactly
#define CQ      (-2.8853900817779268f)   // ALPHA * log2(e) / L = -2*log2(e)

#define CPR     1064             // region stride (elems) for shifted copies

typedef short  short8 __attribute__((ext_vector_type(8)));
typedef float  f32x16 __attribute__((ext_vector_type(16)));
typedef unsigned int uintx4 __attribute__((ext_vector_type(4)));

union V8 { short8 s; uintx4 u; };

__device__ __forceinline__ unsigned int bf16h(float f) {
    unsigned int b = __float_as_uint(f);
    return (b + 0x7FFFu + ((b >> 16) & 1u)) >> 16;   // RNE to bf16 (finite inputs)
}
__device__ __forceinline__ float bf16back(unsigned int h) {
    return __uint_as_float(h << 16);
}

__global__ __launch_bounds__(512, 2)
void softmin_mfma_kernel(const float* __restrict__ x,
                         const float* __restrict__ sh,
                         float* __restrict__ out) {
    // 16 regions (r=0..7 x half=hi/lo) of CPR shorts: cp[(2r+half)*CPR + e] = x_half[e + r]
    __shared__ __align__(16) short cp[16 * CPR];          // 34,048 B
    __shared__ __align__(16) float lds_xf[1056];          //  4,224 B
    __shared__ __align__(16) float lds_sqw[992];          //  3,968 B (974.. = PAD_SQ)
    __shared__ __align__(16) float gmT[256];              //  1,024 B  [jh][kt][col]
    __shared__ __align__(16) float redM[256];             //  1,024 B
    __shared__ __align__(16) float redS[256];             //  1,024 B
    __shared__ __align__(16) float redT[256];             //  1,024 B
    // total 46,336 B -> 2 blocks/CU

    const int i    = blockIdx.x;
    const int tid  = threadIdx.x;
    const int lane = tid & 63;
    const int w    = tid >> 6;     // wave 0..7
    const int kt   = w & 3;        // k-tile 0..3 (32 cols each)
    const int jh   = w >> 2;       // j-half 0/1
    const int col  = lane & 31;
    const int hi   = lane >> 5;

    // ---- B fragments for this wave's k-tile: 4 frags of K=16 (hi + lo) ----
    // B[kappa][n]: lane holds n = kt*32 + col, kappa = 16*km + 8*hi + e.
    short8 bh[4], bl[4];
    {
        const int n = kt * 32 + col;
        const bool nok = (n < K_SH);
        const float* srow = sh + (nok ? n : 0) * L_SH;
        #pragma unroll
        for (int km = 0; km < 4; ++km) {
            const int k0 = 16 * km + 8 * hi;
            float sv[8];
            #pragma unroll
            for (int e = 0; e < 8; ++e) sv[e] = 0.f;
            if (nok) {
                #pragma unroll
                for (int e = 0; e < 8; e += 2) {
                    if (k0 + e < L_SH) {          // pairs even-aligned, L even
                        float2 v = *(const float2*)(srow + k0 + e);
                        sv[e] = v.x; sv[e + 1] = v.y;
                    }
                }
            }
            unsigned int hb[8], lb[8];
            #pragma unroll
            for (int e = 0; e < 8; ++e) {
                hb[e] = bf16h(sv[e]);
                lb[e] = bf16h(sv[e] - bf16back(hb[e]));
            }
            V8 H, Lo;
            H.u  = uintx4{hb[0]|(hb[1]<<16), hb[2]|(hb[3]<<16), hb[4]|(hb[5]<<16), hb[6]|(hb[7]<<16)};
            Lo.u = uintx4{lb[0]|(lb[1]<<16), lb[2]|(lb[3]<<16), lb[4]|(lb[5]<<16), lb[6]|(lb[7]<<16)};
            bh[km] = H.s; bl[km] = Lo.s;
        }
    }

    // ---- stage x row (f32) into LDS, zero-pad to 1056 ----
    {
        const float4* gx = (const float4*)(x + (size_t)i * Q_LEN);
        float4* lx = (float4*)lds_xf;
        if (tid < 256) lx[tid] = gx[tid];
        if (tid < 8)   lx[256 + tid] = make_float4(0.f, 0.f, 0.f, 0.f);
    }
    __syncthreads();

    // ---- sq_win (exact fp32, sliding within groups of 4), rows 0..991 ----
    if (tid < 248) {
        const float4* xf4 = (const float4*)lds_xf;
        float r0, r1, r2, r3;
        if (tid < 244) {
            float v[56];
            #pragma unroll
            for (int q = 0; q < 14; ++q) {
                float4 a = xf4[tid + q];
                v[4*q] = a.x; v[4*q+1] = a.y; v[4*q+2] = a.z; v[4*q+3] = a.w;
            }
            float s0 = 0.f;
            #pragma unroll
            for (int l = 0; l < L_SH; ++l) s0 = fmaf(v[l], v[l], s0);
            float s1 = fmaf(v[50], v[50], s0 - v[0]*v[0]);
            float s2 = fmaf(v[51], v[51], s1 - v[1]*v[1]);
            float s3 = fmaf(v[52], v[52], s2 - v[2]*v[2]);
            r0 = s0; r1 = s1; r2 = s2; r3 = s3;
            if (4*tid + 2 >= J_WIN) r2 = PAD_SQ;            // j = 974
            if (4*tid + 3 >= J_WIN) r3 = PAD_SQ;            // j = 975
        } else {
            r0 = r1 = r2 = r3 = PAD_SQ;                     // j 976..991
        }
        *(float4*)&lds_sqw[4*tid] = make_float4(r0, r1, r2, r3);
    }

    // ---- base bf16 hi/lo arrays (copy r=0) ----
    if (tid < 132) {
        const float4* xf4 = (const float4*)lds_xf;
        float4 a = xf4[2*tid], b = xf4[2*tid + 1];
        float xv[8] = {a.x, a.y, a.z, a.w, b.x, b.y, b.z, b.w};
        unsigned int hh[8], rr[8];
        #pragma unroll
        for (int e = 0; e < 8; ++e) {
            hh[e] = bf16h(xv[e]);
            rr[e] = bf16h(xv[e] - bf16back(hh[e]));
        }
        *(uintx4*)&cp[8*tid] =
            uintx4{hh[0]|(hh[1]<<16), hh[2]|(hh[3]<<16), hh[4]|(hh[5]<<16), hh[6]|(hh[7]<<16)};
        *(uintx4*)&cp[CPR + 8*tid] =
            uintx4{rr[0]|(rr[1]<<16), rr[2]|(rr[3]<<16), rr[4]|(rr[5]<<16), rr[6]|(rr[7]<<16)};
    }
    __syncthreads();

    // ---- shifted copies r=1..7 via aligned reads + 16-bit funnel shifts ----
    if (tid < 262) {                                         // 131 blocks x 2 halves
        const int half = tid & 1, blk = tid >> 1;
        const uintx4 A  = *(const uintx4*)&cp[half*CPR + 8*blk];
        const uintx4 B4 = *(const uintx4*)&cp[half*CPR + 8*blk + 8];
        unsigned int s[8] = {A[0], A[1], A[2], A[3], B4[0], B4[1], B4[2], B4[3]};
        #pragma unroll
        for (int r = 1; r < 8; ++r) {
            const int p = r >> 1;
            unsigned int o[4];
            if ((r & 1) == 0) {
                #pragma unroll
                for (int e = 0; e < 4; ++e) o[e] = s[p + e];
            } else {
                #pragma unroll
                for (int e = 0; e < 4; ++e) o[e] = (s[p + e] >> 16) | (s[p + e + 1] << 16);
            }
            *(uintx4*)&cp[(2*r + half)*CPR + 8*blk] = uintx4{o[0], o[1], o[2], o[3]};
        }
    }
    __syncthreads();

    // A frag (32x32x16): elem e <-> x[j0 + (lane&31) + 16*km + 8*(lane>>5) + e]
    // start mod 8 == lane&7 -> copy r = lane&7 at 8-aligned offset.
    const int r7       = lane & 7;
    const int lane_off = 8 * ((lane >> 3) & 3) + 8 * hi;
    const int abase0   = (2 * r7) * CPR + lane_off;

    // ======== PASS 1: hi*hi approximate min over this half's j-tiles ========
    float mreg = 1e30f;
    for (int mt = jh; mt < MT32; mt += 2) {
        const int j0 = mt << 5;
        const int p  = abase0 + j0;
        const short8 ah0 = *(const short8*)&cp[p];
        const short8 ah1 = *(const short8*)&cp[p + 16];
        const short8 ah2 = *(const short8*)&cp[p + 32];
        const short8 ah3 = *(const short8*)&cp[p + 48];

        f32x16 acc = {0.f,0.f,0.f,0.f,0.f,0.f,0.f,0.f,0.f,0.f,0.f,0.f,0.f,0.f,0.f,0.f};
        acc = __builtin_amdgcn_mfma_f32_32x32x16_bf16(ah0, bh[0], acc, 0, 0, 0);
        acc = __builtin_amdgcn_mfma_f32_32x32x16_bf16(ah1, bh[1], acc, 0, 0, 0);
        acc = __builtin_amdgcn_mfma_f32_32x32x16_bf16(ah2, bh[2], acc, 0, 0, 0);
        acc = __builtin_amdgcn_mfma_f32_32x32x16_bf16(ah3, bh[3], acc, 0, 0, 0);

        #pragma unroll
        for (int rg = 0; rg < 4; ++rg) {
            const float4 sqv = *(const float4*)&lds_sqw[j0 + 8*rg + 4*hi];
            const float q0 = fmaf(acc[4*rg+0], -2.f, sqv.x);
            const float q1 = fmaf(acc[4*rg+1], -2.f, sqv.y);
            const float q2 = fmaf(acc[4*rg+2], -2.f, sqv.z);
            const float q3 = fmaf(acc[4*rg+3], -2.f, sqv.w);
            mreg = fminf(mreg, fminf(fminf(q0, q1), fminf(q2, q3)));
        }
    }
    mreg = fminf(mreg, __shfl_xor(mreg, 32));    // rows split across hi halves
    if (lane < 32) gmT[(jh * 4 + kt) * 32 + lane] = mreg;
    __syncthreads();
    const float mq = fminf(gmT[kt * 32 + col], gmT[128 + kt * 32 + col]);

    // ======== PASS 2: full 12-MFMA hi/lo GEMM + branchless weights ========
    float S = 0.f, T = 0.f, tmin = 1e30f;
    for (int mt = jh; mt < MT32; mt += 2) {
        const int j0 = mt << 5;
        const int p  = abase0 + j0;
        const short8 ah0 = *(const short8*)&cp[p];
        const short8 ah1 = *(const short8*)&cp[p + 16];
        const short8 ah2 = *(const short8*)&cp[p + 32];
        const short8 ah3 = *(const short8*)&cp[p + 48];
        const short8 al0 = *(const short8*)&cp[p + CPR];
        const short8 al1 = *(const short8*)&cp[p + CPR + 16];
        const short8 al2 = *(const short8*)&cp[p + CPR + 32];
        const short8 al3 = *(const short8*)&cp[p + CPR + 48];

        f32x16 acc = {0.f,0.f,0.f,0.f,0.f,0.f,0.f,0.f,0.f,0.f,0.f,0.f,0.f,0.f,0.f,0.f};
        acc = __builtin_amdgcn_mfma_f32_32x32x16_bf16(ah0, bh[0], acc, 0, 0, 0);
        acc = __builtin_amdgcn_mfma_f32_32x32x16_bf16(ah1, bh[1], acc, 0, 0, 0);
        acc = __builtin_amdgcn_mfma_f32_32x32x16_bf16(ah2, bh[2], acc, 0, 0, 0);
        acc = __builtin_amdgcn_mfma_f32_32x32x16_bf16(ah3, bh[3], acc, 0, 0, 0);
        acc = __builtin_amdgcn_mfma_f32_32x32x16_bf16(al0, bh[0], acc, 0, 0, 0);
        acc = __builtin_amdgcn_mfma_f32_32x32x16_bf16(al1, bh[1], acc, 0, 0, 0);
        acc = __builtin_amdgcn_mfma_f32_32x32x16_bf16(al2, bh[2], acc, 0, 0, 0);
        acc = __builtin_amdgcn_mfma_f32_32x32x16_bf16(al3, bh[3], acc, 0, 0, 0);
        acc = __builtin_amdgcn_mfma_f32_32x32x16_bf16(ah0, bl[0], acc, 0, 0, 0);
        acc = __builtin_amdgcn_mfma_f32_32x32x16_bf16(ah1, bl[1], acc, 0, 0, 0);
        acc = __builtin_amdgcn_mfma_f32_32x32x16_bf16(ah2, bl[2], acc, 0, 0, 0);
        acc = __builtin_amdgcn_mfma_f32_32x32x16_bf16(ah3, bl[3], acc, 0, 0, 0);

        #pragma unroll
        for (int rg = 0; rg < 4; ++rg) {
            const float4 sqv = *(const float4*)&lds_sqw[j0 + 8*rg + 4*hi];
            const float s0 = sqv.x - mq, s1 = sqv.y - mq;
            const float s2 = sqv.z - mq, s3 = sqv.w - mq;
            const float t0 = fmaf(acc[4*rg+0], -2.f, s0);
            const float t1 = fmaf(acc[4*rg+1], -2.f, s1);
            const float t2 = fmaf(acc[4*rg+2], -2.f, s2);
            const float t3 = fmaf(acc[4*rg+3], -2.f, s3);
            tmin = fminf(tmin, fminf(fminf(t0, t1), fminf(t2, t3)));
            const float w0 = exp2f(t0 * CQ);
            const float w1 = exp2f(t1 * CQ);
            const float w2 = exp2f(t2 * CQ);
            const float w3 = exp2f(t3 * CQ);
            S += (w0 + w1) + (w2 + w3);
            float tv = T;
            tv = fmaf(t0, w0, tv);
            tv = fmaf(t1, w1, tv);
            tv = fmaf(t2, w2, tv);
            tv = fmaf(t3, w3, tv);
            T = tv;
        }
    }

    // ---- wave-local reduce (mq shared across merged lanes -> plain sums) ----
    tmin = fminf(tmin, __shfl_xor(tmin, 32));
    S += __shfl_xor(S, 32);
    T += __shfl_xor(T, 32);
    if (lane < 32) {
        const int idx = (jh * 4 + kt) * 32 + lane;
        redM[idx] = tmin; redS[idx] = S; redT[idx] = T;
    }
    __syncthreads();

    // ---- merge the two j-halves + write:  M = (T/S - tmin) / L ----
    if (tid < 128) {
        const float tm = fminf(redM[tid], redM[128 + tid]);
        const float Sf = redS[tid] + redS[128 + tid];
        const float Tf = redT[tid] + redT[128 + tid];
        // k = (tid>>5)*32 + (tid&31) == tid
        if (tid < K_SH) out[(size_t)i * K_SH + tid] = (Tf / Sf - tm) * RINV_L;
    }
}

extern "C" void kernel_launch(void* const* d_in, const int* in_sizes, int n_in,
                              void* d_out, int out_size, void* d_ws, size_t ws_size,
                              hipStream_t stream) {
    const float* x  = (const float*)d_in[0];   // (512, 1024) f32
    const float* sh = (const float*)d_in[1];   // (100, 50)  f32
    float* out = (float*)d_out;                // (512, 100) f32

    softmin_mfma_kernel<<<N_SEQ, 512, 0, stream>>>(x, sh, out);
}